// Round 1
// 3622.802 us; speedup vs baseline: 1.0993x; 1.0993x over previous
//
#include <hip/hip_runtime.h>

// Voxelizer: B=2, C=32 -> BC=64 channels, N=1e6 points, V=262144 voxels.
// Accumulator layout is TRANSPOSED vs v1: sums[v][bc] (row = 256B contiguous).
// One point's 64 channel-atomics hit 4 consecutive cache lines instead of 64
// random ones -> sector-hit RMWs instead of 64 independent line RMWs.
// ws layout: [ sums: V*BC floats | counts: V floats ] = 68,157,440 bytes.

constexpr int BC  = 64;         // B*C
constexpr int VOX = 262144;     // num_voxels (harness constant)

__global__ __launch_bounds__(256) void voxel_scatter(
    const float* __restrict__ feat, const int* __restrict__ idx,
    float* __restrict__ sums, float* __restrict__ counts, int N)
{
    int p = blockIdx.x * blockDim.x + threadIdx.x;
    if (p >= N) return;
    int v = idx[p];

    atomicAdd(&counts[v], 1.0f);

    // Row base: one address calc; the 64 atomics are base + imm offset (bc*4).
    float* row = sums + (size_t)v * BC;
    #pragma unroll
    for (int bc = 0; bc < BC; ++bc) {
        // coalesced: fixed bc, consecutive p across lanes
        float f = feat[(size_t)bc * N + p];
        atomicAdd(&row[bc], f);   // lanes hit the same 64 lines for 16 consecutive instrs
    }
}

__global__ __launch_bounds__(256) void voxel_gather(
    const float* __restrict__ sums, const float* __restrict__ counts,
    const int* __restrict__ idx, float* __restrict__ out, int N)
{
    int p = blockIdx.x * blockDim.x + threadIdx.x;
    if (p >= N) return;
    int v = idx[p];

    float inv = 1.0f / fmaxf(counts[v], 1.0f);

    // Contiguous 256B row read per point (16 x float4), LLC-resident.
    const float4* row = (const float4*)(sums + (size_t)v * BC);
    #pragma unroll
    for (int q = 0; q < BC / 4; ++q) {
        float4 r = row[q];
        // coalesced: fixed channel, consecutive p across lanes
        out[(size_t)(4 * q + 0) * N + p] = r.x * inv;
        out[(size_t)(4 * q + 1) * N + p] = r.y * inv;
        out[(size_t)(4 * q + 2) * N + p] = r.z * inv;
        out[(size_t)(4 * q + 3) * N + p] = r.w * inv;
    }
}

extern "C" void kernel_launch(void* const* d_in, const int* in_sizes, int n_in,
                              void* d_out, int out_size, void* d_ws, size_t ws_size,
                              hipStream_t stream) {
    const float* feat = (const float*)d_in[0];
    const int* idx = (const int*)d_in[1];
    float* out = (float*)d_out;
    int N = in_sizes[1];                 // 1,000,000

    float* sums = (float*)d_ws;                       // V*BC floats, [v][bc]
    float* counts = sums + (size_t)VOX * BC;          // V floats
    size_t zero_bytes = ((size_t)VOX * BC + VOX) * sizeof(float);

    hipMemsetAsync(d_ws, 0, zero_bytes, stream);

    int blocks = (N + 255) / 256;        // thread per point
    voxel_scatter<<<blocks, 256, 0, stream>>>(feat, idx, sums, counts, N);
    voxel_gather<<<blocks, 256, 0, stream>>>(sums, counts, idx, out, N);
}

// Round 3
// 1605.937 us; speedup vs baseline: 2.4799x; 2.2559x over previous
//
#include <hip/hip_runtime.h>

// Voxelizer: B=2, C=32 -> BC=64 channels, N=1e6 points, V=262144 voxels.
// v4 = v3 (counting-sort + segmented reduce) with hardened scratch layout.
//
// v2 measurement: 64M device atomics run at ~20 G/s regardless of address
// locality (WRITE_SIZE pinned at 64M x 32B sector-RMWs). So: eliminate them.
//   hist(1M int atomics) -> in-place scan -> scatter_ids(1M atomics)
//   -> reduce_mean (0 atomics, coalesced writes) -> gather.
//
// ws layout (exactly 68,157,440 B, the proven budget):
//   mean   : float[V*BC] @ 0          (67,108,864 B)  [v][bc] rows
//   cursor : int[V]      @ 67,108,864 ( 1,048,576 B)  hist->scan->end-offsets
// d_out head as scratch (dead until gather fully overwrites out):
//   order   : int[N]   @ 0         (4,000,000 B)  point ids in voxel order
//   partials: int[NSB] @ 4,000,000 (    1,024 B)

constexpr int BC  = 64;
constexpr int VOX = 262144;
constexpr int SCAN_BLK = 1024;            // elements per scan block
constexpr int NSB = VOX / SCAN_BLK;       // 256
constexpr int RV = 128;                   // voxels per reduce block

__global__ __launch_bounds__(256) void hist_kernel(
    const int* __restrict__ idx, int* __restrict__ cursor, int N)
{
    int t = blockIdx.x * 256 + threadIdx.x;
    int n0 = t * 4;
    if (n0 >= N) return;
    int4 vi = *(const int4*)(idx + n0);
    atomicAdd(&cursor[vi.x], 1);
    atomicAdd(&cursor[vi.y], 1);
    atomicAdd(&cursor[vi.z], 1);
    atomicAdd(&cursor[vi.w], 1);
}

// In-place exclusive scan of cursor (each thread only reads its own int4
// before writing, so in-place across the block is safe).
__global__ __launch_bounds__(256) void scan_blocks(
    int* __restrict__ cursor, int* __restrict__ partials)
{
    __shared__ int sm[256];
    int t = threadIdx.x, b = blockIdx.x;
    int base = b * SCAN_BLK + t * 4;
    int4 c = *(const int4*)(cursor + base);
    int s = c.x + c.y + c.z + c.w;
    sm[t] = s;
    __syncthreads();
    #pragma unroll
    for (int off = 1; off < 256; off <<= 1) {
        int add = (t >= off) ? sm[t - off] : 0;
        __syncthreads();
        sm[t] += add;
        __syncthreads();
    }
    int excl = sm[t] - s;                 // exclusive within block
    int4 o;
    o.x = excl; o.y = excl + c.x; o.z = o.y + c.y; o.w = o.z + c.z;
    *(int4*)(cursor + base) = o;
    if (t == 255) partials[b] = sm[255];  // block total
}

__global__ __launch_bounds__(256) void scan_partials(int* __restrict__ partials)
{
    __shared__ int sm[256];
    int t = threadIdx.x;
    int v = partials[t];
    sm[t] = v;
    __syncthreads();
    #pragma unroll
    for (int off = 1; off < 256; off <<= 1) {
        int add = (t >= off) ? sm[t - off] : 0;
        __syncthreads();
        sm[t] += add;
        __syncthreads();
    }
    partials[t] = sm[t] - v;              // exclusive
}

__global__ __launch_bounds__(256) void scan_add(
    int* __restrict__ cursor, const int* __restrict__ partials)
{
    int t = blockIdx.x * 256 + threadIdx.x;
    int base = t * 4;                     // 1024 % 4 == 0 -> same partial
    int add = partials[base >> 10];
    int4 c = *(int4*)(cursor + base);
    c.x += add; c.y += add; c.z += add; c.w += add;
    *(int4*)(cursor + base) = c;
}

__global__ __launch_bounds__(256) void scatter_ids(
    const int* __restrict__ idx, int* __restrict__ cursor,
    int* __restrict__ order, int N)
{
    int t = blockIdx.x * 256 + threadIdx.x;
    int n0 = t * 4;
    if (n0 >= N) return;
    int4 vi = *(const int4*)(idx + n0);
    int p0 = atomicAdd(&cursor[vi.x], 1); order[p0] = n0;
    int p1 = atomicAdd(&cursor[vi.y], 1); order[p1] = n0 + 1;
    int p2 = atomicAdd(&cursor[vi.z], 1); order[p2] = n0 + 2;
    int p3 = atomicAdd(&cursor[vi.w], 1); order[p3] = n0 + 3;
    // after this kernel: cursor[v] == END offset of voxel v's segment
}

// Block = 256 threads over RV=128 voxels. Thread (vL = t&127, half = t>>7)
// sums channels [half*32, half*32+32) for its voxel; zero atomics. Output
// goes through an LDS transpose tile -> one contiguous 32KB coalesced burst.
__global__ __launch_bounds__(256) void reduce_mean(
    const float* __restrict__ feat, const int* __restrict__ order,
    const int* __restrict__ cursor, float* __restrict__ mean, int N)
{
    __shared__ float tile[BC][RV + 1];    // +1 pad: conflict-free transpose
    int t = threadIdx.x;
    int vL = t & (RV - 1);
    int half = t >> 7;
    int v0 = blockIdx.x * RV;
    int v = v0 + vL;

    int end = cursor[v];
    int start = (v > 0) ? cursor[v - 1] : 0;   // segments are contiguous
    int cnt = end - start;
    float inv = 1.0f / fmaxf((float)cnt, 1.0f);

    // register-cache first 8 point ids (covers the vast majority of voxels)
    int pid[8];
    #pragma unroll
    for (int i = 0; i < 8; ++i) pid[i] = (start + i < end) ? order[start + i] : 0;

    int bc0 = half * 32;
    for (int bci = 0; bci < 32; ++bci) {
        int bc = bc0 + bci;
        const float* f = feat + (size_t)bc * N;
        float s = 0.f;
        #pragma unroll
        for (int i = 0; i < 8; ++i) if (i < cnt) s += f[pid[i]];
        for (int j = start + 8; j < end; ++j) s += f[order[j]];
        tile[bc][vL] = s * inv;
    }
    __syncthreads();

    // block output: mean[v0..v0+128)[0..64) = 32KB contiguous = 2048 float4
    float* dst = mean + (size_t)v0 * BC;
    #pragma unroll
    for (int k = 0; k < 8; ++k) {
        int lin4 = t + 256 * k;           // float4 index in [0, 2048)
        int vv = lin4 >> 4;               // voxel-local
        int cc = (lin4 & 15) * 4;         // channel base
        float4 o;
        o.x = tile[cc + 0][vv];
        o.y = tile[cc + 1][vv];
        o.z = tile[cc + 2][vv];
        o.w = tile[cc + 3][vv];
        *(float4*)(dst + (size_t)lin4 * 4) = o;
    }
}

__global__ __launch_bounds__(256) void voxel_gather(
    const float* __restrict__ mean, const int* __restrict__ idx,
    float* __restrict__ out, int N)
{
    int p = blockIdx.x * 256 + threadIdx.x;
    if (p >= N) return;
    int v = idx[p];
    const float4* row = (const float4*)(mean + (size_t)v * BC);
    #pragma unroll
    for (int q = 0; q < 16; ++q) {
        float4 r = row[q];                // 4 lines/thread, L1-reused across q
        // streaming stores: out is never re-read; keep mean resident in L2/L3
        __builtin_nontemporal_store(r.x, &out[(size_t)(4 * q + 0) * N + p]);
        __builtin_nontemporal_store(r.y, &out[(size_t)(4 * q + 1) * N + p]);
        __builtin_nontemporal_store(r.z, &out[(size_t)(4 * q + 2) * N + p]);
        __builtin_nontemporal_store(r.w, &out[(size_t)(4 * q + 3) * N + p]);
    }
}

extern "C" void kernel_launch(void* const* d_in, const int* in_sizes, int n_in,
                              void* d_out, int out_size, void* d_ws, size_t ws_size,
                              hipStream_t stream) {
    const float* feat = (const float*)d_in[0];
    const int* idx = (const int*)d_in[1];
    float* out = (float*)d_out;
    int N = in_sizes[1];                  // 1,000,000

    // ws: mean (64MB) + cursor (1MB) == 68,157,440 B exactly
    float* mean = (float*)d_ws;
    int* cursor = (int*)((char*)d_ws + (size_t)VOX * BC * sizeof(float));

    // d_out head as scratch (fully dead until gather overwrites all of out)
    char* ob = (char*)d_out;
    int* order    = (int*)(ob);                   // 4,000,000 B
    int* partials = (int*)(ob + 4000000);         //     1,024 B

    hipMemsetAsync(cursor, 0, (size_t)VOX * sizeof(int), stream);

    int pthreads = (N + 3) / 4;           // 250,000
    int pblocks = (pthreads + 255) / 256; // 977

    hist_kernel  <<<pblocks, 256, 0, stream>>>(idx, cursor, N);
    scan_blocks  <<<NSB, 256, 0, stream>>>(cursor, partials);
    scan_partials<<<1, 256, 0, stream>>>(partials);
    scan_add     <<<VOX / SCAN_BLK, 256, 0, stream>>>(cursor, partials);
    scatter_ids  <<<pblocks, 256, 0, stream>>>(idx, cursor, order, N);
    reduce_mean  <<<VOX / RV, 256, 0, stream>>>(feat, order, cursor, mean, N);
    voxel_gather <<<(N + 255) / 256, 256, 0, stream>>>(mean, idx, out, N);
}

// Round 4
// 781.563 us; speedup vs baseline: 5.0957x; 2.0548x over previous
//
#include <hip/hip_runtime.h>

// Voxelizer: B=2, C=32 -> BC=64 channels, N=1e6 points, V=262144 voxels.
// v5: physically sort features into voxel order (point-major 256B rows), then
// segment-reduce over a STREAMING read. v4's reduce fetched 3.74GB for 256MB
// of payload (random 4B reads x 64B lines = 15x over-fetch, 1126us); sorting
// first makes every fetched byte payload.
//
// Pipeline: hist(1M atomics) -> in-place scan -> permute_scatter(1M atomics,
// coalesced feat read, 256B row writes) -> reduce_mean(streaming, 0 atomics)
// -> gather.
//
// ws (exactly 68,157,440 B, proven budget):
//   mean   : float[V*BC] @ 0          (67,108,864 B) [v][bc] rows
//   cursor : int[V]      @ 67,108,864 ( 1,048,576 B)
//   partials aliases mean[0..255] (dead until reduce_mean, after scan ends)
// d_out (256,000,000 B) holds sorted[N][BC] until the final gather overwrites.

constexpr int BC  = 64;
constexpr int VOX = 262144;
constexpr int SCAN_BLK = 1024;            // elements per scan block
constexpr int NSB = VOX / SCAN_BLK;       // 256
constexpr int RV  = 128;                  // voxels per reduce block

__global__ __launch_bounds__(256) void hist_kernel(
    const int* __restrict__ idx, int* __restrict__ cursor, int N)
{
    int t = blockIdx.x * 256 + threadIdx.x;
    int n0 = t * 4;
    if (n0 >= N) return;
    int4 vi = *(const int4*)(idx + n0);
    atomicAdd(&cursor[vi.x], 1);
    atomicAdd(&cursor[vi.y], 1);
    atomicAdd(&cursor[vi.z], 1);
    atomicAdd(&cursor[vi.w], 1);
}

// In-place exclusive scan of cursor (each thread reads only its own int4
// before writing -> in-place safe).
__global__ __launch_bounds__(256) void scan_blocks(
    int* __restrict__ cursor, int* __restrict__ partials)
{
    __shared__ int sm[256];
    int t = threadIdx.x, b = blockIdx.x;
    int base = b * SCAN_BLK + t * 4;
    int4 c = *(const int4*)(cursor + base);
    int s = c.x + c.y + c.z + c.w;
    sm[t] = s;
    __syncthreads();
    #pragma unroll
    for (int off = 1; off < 256; off <<= 1) {
        int add = (t >= off) ? sm[t - off] : 0;
        __syncthreads();
        sm[t] += add;
        __syncthreads();
    }
    int excl = sm[t] - s;
    int4 o;
    o.x = excl; o.y = excl + c.x; o.z = o.y + c.y; o.w = o.z + c.z;
    *(int4*)(cursor + base) = o;
    if (t == 255) partials[b] = sm[255];
}

__global__ __launch_bounds__(256) void scan_partials(int* __restrict__ partials)
{
    __shared__ int sm[256];
    int t = threadIdx.x;
    int v = partials[t];
    sm[t] = v;
    __syncthreads();
    #pragma unroll
    for (int off = 1; off < 256; off <<= 1) {
        int add = (t >= off) ? sm[t - off] : 0;
        __syncthreads();
        sm[t] += add;
        __syncthreads();
    }
    partials[t] = sm[t] - v;              // exclusive
}

__global__ __launch_bounds__(256) void scan_add(
    int* __restrict__ cursor, const int* __restrict__ partials)
{
    int t = blockIdx.x * 256 + threadIdx.x;
    int base = t * 4;                     // 1024 % 4 == 0 -> same partial
    int add = partials[base >> 10];
    int4 c = *(int4*)(cursor + base);
    c.x += add; c.y += add; c.z += add; c.w += add;
    *(int4*)(cursor + base) = c;
}

// Per point p: allocate slot j in its voxel's segment, gather the point's 64
// channels (coalesced across lanes: fixed bc, consecutive p), write one
// contiguous 256B row sorted[j][0..63].
__global__ __launch_bounds__(256) void permute_scatter(
    const float* __restrict__ feat, const int* __restrict__ idx,
    int* __restrict__ cursor, float* __restrict__ sorted, int N)
{
    int p = blockIdx.x * 256 + threadIdx.x;
    if (p >= N) return;
    int v = idx[p];
    int j = atomicAdd(&cursor[v], 1);     // after kernel: cursor[v] == end
    float* dst = sorted + (size_t)j * BC; // 256B-aligned row

    #pragma unroll
    for (int c0 = 0; c0 < BC; c0 += 16) { // 16-float chunks: low VGPR
        float f[16];
        #pragma unroll
        for (int k = 0; k < 16; ++k)
            f[k] = feat[(size_t)(c0 + k) * N + p];  // coalesced per instr
        #pragma unroll
        for (int q = 0; q < 4; ++q)
            *(float4*)(dst + c0 + 4 * q) =
                make_float4(f[4*q], f[4*q+1], f[4*q+2], f[4*q+3]);
    }
}

// Block = 256 threads over RV=128 voxels; thread (vL=t&127, half=t>>7) sums
// channels [half*32, half*32+32). Segment reads are contiguous 128B per
// (point,thread) within the block's ~125KB window -> streaming fetch.
__global__ __launch_bounds__(256) void reduce_mean(
    const float* __restrict__ sorted, const int* __restrict__ cursor,
    float* __restrict__ mean)
{
    int t = threadIdx.x;
    int vL = t & (RV - 1);
    int half = t >> 7;
    int v = blockIdx.x * RV + vL;

    int end = cursor[v];
    int start = (v > 0) ? cursor[v - 1] : 0;
    float inv = 1.0f / fmaxf((float)(end - start), 1.0f);

    float4 acc[8] = {};
    for (int j = start; j < end; ++j) {
        const float4* row = (const float4*)(sorted + (size_t)j * BC) + half * 8;
        #pragma unroll
        for (int q = 0; q < 8; ++q) {
            float4 r = row[q];
            acc[q].x += r.x; acc[q].y += r.y; acc[q].z += r.z; acc[q].w += r.w;
        }
    }
    float* dst = mean + (size_t)v * BC + half * 32;
    #pragma unroll
    for (int q = 0; q < 8; ++q) {
        float4 o = make_float4(acc[q].x * inv, acc[q].y * inv,
                               acc[q].z * inv, acc[q].w * inv);
        *(float4*)(dst + 4 * q) = o;      // full-line 256B row writes
    }
}

__global__ __launch_bounds__(256) void voxel_gather(
    const float* __restrict__ mean, const int* __restrict__ idx,
    float* __restrict__ out, int N)
{
    int p = blockIdx.x * 256 + threadIdx.x;
    if (p >= N) return;
    int v = idx[p];
    const float4* row = (const float4*)(mean + (size_t)v * BC);
    #pragma unroll
    for (int q = 0; q < 16; ++q) {
        float4 r = row[q];
        // streaming stores: out never re-read; keep mean resident in L2/L3
        __builtin_nontemporal_store(r.x, &out[(size_t)(4 * q + 0) * N + p]);
        __builtin_nontemporal_store(r.y, &out[(size_t)(4 * q + 1) * N + p]);
        __builtin_nontemporal_store(r.z, &out[(size_t)(4 * q + 2) * N + p]);
        __builtin_nontemporal_store(r.w, &out[(size_t)(4 * q + 3) * N + p]);
    }
}

extern "C" void kernel_launch(void* const* d_in, const int* in_sizes, int n_in,
                              void* d_out, int out_size, void* d_ws, size_t ws_size,
                              hipStream_t stream) {
    const float* feat = (const float*)d_in[0];
    const int* idx = (const int*)d_in[1];
    float* out = (float*)d_out;
    int N = in_sizes[1];                  // 1,000,000

    float* mean = (float*)d_ws;                                   // 64MB
    int* cursor = (int*)((char*)d_ws + (size_t)VOX * BC * 4);     // 1MB
    int* partials = (int*)d_ws;           // aliases mean head; dead until
                                          // reduce_mean (scan is done by then)
    float* sorted = (float*)d_out;        // 256MB; overwritten by gather

    hipMemsetAsync(cursor, 0, (size_t)VOX * sizeof(int), stream);

    int pblocks4 = ((N + 3) / 4 + 255) / 256;   // 977  (4 pts/thread kernels)
    int pblocks1 = (N + 255) / 256;             // 3907 (1 pt/thread kernels)

    hist_kernel    <<<pblocks4, 256, 0, stream>>>(idx, cursor, N);
    scan_blocks    <<<NSB, 256, 0, stream>>>(cursor, partials);
    scan_partials  <<<1, 256, 0, stream>>>(partials);
    scan_add       <<<VOX / SCAN_BLK, 256, 0, stream>>>(cursor, partials);
    permute_scatter<<<pblocks1, 256, 0, stream>>>(feat, idx, cursor, sorted, N);
    reduce_mean    <<<VOX / RV, 256, 0, stream>>>(sorted, cursor, mean);
    voxel_gather   <<<pblocks1, 256, 0, stream>>>(mean, idx, out, N);
}